// Round 1
// baseline (155.248 us; speedup 1.0000x reference)
//
#include <hip/hip_runtime.h>
#include <math.h>

// CellSegmentationLoss: fused focal + dice + boundary-BCE + IoU-aux loss.
// Inputs: d_in[0]=pred_masks (16*1*1024*1024 f32), d_in[1]=gt_masks (same),
//         d_in[2]=pred_iou (16 f32). Output: 1 f32 scalar.
//
// Strategy: memory-bound single pass. 2048 blocks (128 per image so each
// block's pixels belong to exactly one batch), float4 loads, per-thread fp32
// accumulation of 7 quantities, wave shuffle-reduce -> LDS -> 7 atomicAdds
// into per-batch slots in d_ws. Tiny finalize kernel combines 16*7 floats.

#define HW_PIX (1024 * 1024)
#define BATCH 16
constexpr int BLOCKS_PER_IMG = 128;
constexpr int THREADS = 256;
constexpr int PIX_PER_BLOCK = HW_PIX / BLOCKS_PER_IMG;        // 8192
constexpr int ITERS = PIX_PER_BLOCK / (THREADS * 4);          // 8 float4 iters/thread

__global__ __launch_bounds__(THREADS) void
loss_partial(const float* __restrict__ x, const float* __restrict__ t,
             float* __restrict__ acc) {
  const int b = blockIdx.x / BLOCKS_PER_IMG;
  const int chunk = blockIdx.x % BLOCKS_PER_IMG;
  const long base = (long)b * HW_PIX + (long)chunk * PIX_PER_BLOCK;
  const float4* __restrict__ x4 = (const float4*)(x + base);
  const float4* __restrict__ t4 = (const float4*)(t + base);

  float fsum = 0.f, csum = 0.f, isum = 0.f, psum = 0.f, tsum = 0.f,
        bisum = 0.f, bpsum = 0.f;

#pragma unroll
  for (int i = 0; i < ITERS; ++i) {
    float4 xv = x4[threadIdx.x + i * THREADS];
    float4 tv = t4[threadIdx.x + i * THREADS];
    const float* xs = reinterpret_cast<const float*>(&xv);
    const float* ts = reinterpret_cast<const float*>(&tv);
#pragma unroll
    for (int j = 0; j < 4; ++j) {
      const float xx = xs[j];
      const float tt = ts[j];
      // stable softplus pieces: e = exp(-|x|) in (0,1]
      const float e = __expf(-fabsf(xx));
      const float r = __builtin_amdgcn_rcpf(1.0f + e);
      const float p = (xx >= 0.0f) ? r : e * r;          // sigmoid(x)
      const float ce = fmaxf(xx, 0.0f) - xx * tt + __logf(1.0f + e);
      const float om = p + tt - 2.0f * p * tt;           // 1 - p_t
      const float at = 0.75f - 0.5f * tt;                // alpha_t
      fsum += at * ce * om * om;                          // focal numerator
      csum += ce;                                         // boundary numerator
      isum += p * tt;                                     // dice intersection
      psum += p;                                          // dice union (p part)
      tsum += tt;                                         // dice union (t part)
      const float bin = (xx > 0.0f) ? 1.0f : 0.0f;        // p > 0.5 <=> x > 0
      bisum += bin * tt;                                  // IoU intersection
      bpsum += bin;                                       // IoU pred count
    }
  }

  float vals[7] = {fsum, csum, isum, psum, tsum, bisum, bpsum};
  __shared__ float red[THREADS / 64][7];
  const int lane = threadIdx.x & 63;
  const int wave = threadIdx.x >> 6;
#pragma unroll
  for (int k = 0; k < 7; ++k) {
    float v = vals[k];
#pragma unroll
    for (int off = 32; off > 0; off >>= 1) v += __shfl_down(v, off);
    if (lane == 0) red[wave][k] = v;
  }
  __syncthreads();
  if (threadIdx.x < 7) {
    const float s = red[0][threadIdx.x] + red[1][threadIdx.x] +
                    red[2][threadIdx.x] + red[3][threadIdx.x];
    atomicAdd(&acc[b * 7 + threadIdx.x], s);
  }
}

__global__ void loss_final(const float* __restrict__ acc,
                           const float* __restrict__ pred_iou,
                           float* __restrict__ out) {
  constexpr float SMOOTH = 1e-6f;
  const int lane = threadIdx.x;  // one wave (64), lanes 0..15 active
  float F = 0.f, C = 0.f, D = 0.f, Q = 0.f;
  if (lane < BATCH) {
    const float* a = acc + lane * 7;
    F = a[0];
    C = a[1];
    const float I = a[2], P = a[3], T = a[4], BI = a[5], BP = a[6];
    D = (2.0f * I + SMOOTH) / (P + T + SMOOTH);            // dice term
    const float iou = (BI + SMOOTH) / (BP + T - BI + SMOOTH);
    const float d = pred_iou[lane] - iou;
    Q = d * d;
  }
#pragma unroll
  for (int off = 32; off > 0; off >>= 1) {
    F += __shfl_down(F, off);
    C += __shfl_down(C, off);
    D += __shfl_down(D, off);
    Q += __shfl_down(Q, off);
  }
  if (lane == 0) {
    const float invN = 1.0f / (float)((long)BATCH * HW_PIX);
    const float focal = F * invN;
    const float dice = 1.0f - D * (1.0f / (float)BATCH);
    const float half_boundary = C * invN;  // 0.5 * (2.0 * mean(ce))
    const float iou_loss = Q * (1.0f / (float)BATCH);
    out[0] = focal + dice + half_boundary + 0.1f * iou_loss;
  }
}

extern "C" void kernel_launch(void* const* d_in, const int* in_sizes, int n_in,
                              void* d_out, int out_size, void* d_ws,
                              size_t ws_size, hipStream_t stream) {
  const float* x = (const float*)d_in[0];
  const float* t = (const float*)d_in[1];
  const float* piou = (const float*)d_in[2];
  float* acc = (float*)d_ws;

  hipMemsetAsync(acc, 0, BATCH * 7 * sizeof(float), stream);
  loss_partial<<<BATCH * BLOCKS_PER_IMG, THREADS, 0, stream>>>(x, t, acc);
  loss_final<<<1, 64, 0, stream>>>(acc, piou, (float*)d_out);
}

// Round 2
// 151.566 us; speedup vs baseline: 1.0243x; 1.0243x over previous
//
#include <hip/hip_runtime.h>
#include <math.h>

// CellSegmentationLoss: fused focal + dice + boundary-BCE + IoU-aux loss.
// Inputs: d_in[0]=pred_masks (16*1*1024*1024 f32), d_in[1]=gt_masks (same),
//         d_in[2]=pred_iou (16 f32). Output: 1 f32 scalar.
//
// R2: latency-bound fix. All 8 float4 loads per thread issued before any
// compute (8 outstanding VMEM/wave), 4096 small blocks for churn, integer
// counts (t-sum, bin-sum, bin*t-sum) moved to SALU via ballot+popcount.

#define HW_PIX (1024 * 1024)
#define BATCH 16
constexpr int BLOCKS_PER_IMG = 256;
constexpr int THREADS = 256;
constexpr int PIX_PER_BLOCK = HW_PIX / BLOCKS_PER_IMG;        // 4096
constexpr int ITERS = PIX_PER_BLOCK / (THREADS * 4);          // 4 float4/thread/array

__global__ __launch_bounds__(THREADS) void
loss_partial(const float* __restrict__ x, const float* __restrict__ t,
             float* __restrict__ acc) {
  const int b = blockIdx.x / BLOCKS_PER_IMG;
  const int chunk = blockIdx.x % BLOCKS_PER_IMG;
  const long base = (long)b * HW_PIX + (long)chunk * PIX_PER_BLOCK;
  const float4* __restrict__ x4 = (const float4*)(x + base);
  const float4* __restrict__ t4 = (const float4*)(t + base);

  // Issue ALL loads before any compute: 8 outstanding float4 loads per wave.
  float4 xv[ITERS], tv[ITERS];
#pragma unroll
  for (int i = 0; i < ITERS; ++i) {
    xv[i] = x4[threadIdx.x + i * THREADS];
    tv[i] = t4[threadIdx.x + i * THREADS];
  }

  float fsum = 0.f, csum = 0.f, isum = 0.f, psum = 0.f;
  unsigned tcnt = 0, bicnt = 0, bpcnt = 0;   // wave-uniform (ballot counts)

#pragma unroll
  for (int i = 0; i < ITERS; ++i) {
    const float* xs = reinterpret_cast<const float*>(&xv[i]);
    const float* ts = reinterpret_cast<const float*>(&tv[i]);
#pragma unroll
    for (int j = 0; j < 4; ++j) {
      const float xx = xs[j];
      const float tt = ts[j];
      const float e = __expf(-fabsf(xx));               // exp(-|x|) in (0,1]
      const float s = 1.0f + e;
      const float r = __builtin_amdgcn_rcpf(s);
      const float p = (xx >= 0.0f) ? r : e * r;          // sigmoid(x)
      const float ce = fmaxf(xx, 0.0f) - xx * tt + __logf(s);
      const float om = fmaf(tt, 1.0f - 2.0f * p, p);     // 1 - p_t
      const float at = 0.75f - 0.5f * tt;                // alpha_t
      fsum += at * ce * om * om;
      csum += ce;
      isum = fmaf(p, tt, isum);
      psum += p;
      const unsigned long long mt = __ballot(tt != 0.0f);
      const unsigned long long mb = __ballot(xx > 0.0f); // p>0.5 <=> x>0
      tcnt  += (unsigned)__popcll(mt);
      bpcnt += (unsigned)__popcll(mb);
      bicnt += (unsigned)__popcll(mt & mb);
    }
  }

  __shared__ float red[THREADS / 64][7];
  const int lane = threadIdx.x & 63;
  const int wave = threadIdx.x >> 6;
  float vals[4] = {fsum, csum, isum, psum};
#pragma unroll
  for (int k = 0; k < 4; ++k) {
    float v = vals[k];
#pragma unroll
    for (int off = 32; off > 0; off >>= 1) v += __shfl_down(v, off);
    if (lane == 0) red[wave][k] = v;
  }
  if (lane == 0) {                 // counts are already wave totals
    red[wave][4] = (float)tcnt;
    red[wave][5] = (float)bicnt;
    red[wave][6] = (float)bpcnt;
  }
  __syncthreads();
  if (threadIdx.x < 7) {
    const float s = red[0][threadIdx.x] + red[1][threadIdx.x] +
                    red[2][threadIdx.x] + red[3][threadIdx.x];
    atomicAdd(&acc[b * 7 + threadIdx.x], s);
  }
}

__global__ void loss_final(const float* __restrict__ acc,
                           const float* __restrict__ pred_iou,
                           float* __restrict__ out) {
  constexpr float SMOOTH = 1e-6f;
  const int lane = threadIdx.x;  // one wave (64), lanes 0..15 active
  float F = 0.f, C = 0.f, D = 0.f, Q = 0.f;
  if (lane < BATCH) {
    const float* a = acc + lane * 7;
    F = a[0];
    C = a[1];
    const float I = a[2], P = a[3], T = a[4], BI = a[5], BP = a[6];
    D = (2.0f * I + SMOOTH) / (P + T + SMOOTH);            // dice term
    const float iou = (BI + SMOOTH) / (BP + T - BI + SMOOTH);
    const float d = pred_iou[lane] - iou;
    Q = d * d;
  }
#pragma unroll
  for (int off = 32; off > 0; off >>= 1) {
    F += __shfl_down(F, off);
    C += __shfl_down(C, off);
    D += __shfl_down(D, off);
    Q += __shfl_down(Q, off);
  }
  if (lane == 0) {
    const float invN = 1.0f / (float)((long)BATCH * HW_PIX);
    const float focal = F * invN;
    const float dice = 1.0f - D * (1.0f / (float)BATCH);
    const float half_boundary = C * invN;  // 0.5 * (2.0 * mean(ce))
    const float iou_loss = Q * (1.0f / (float)BATCH);
    out[0] = focal + dice + half_boundary + 0.1f * iou_loss;
  }
}

extern "C" void kernel_launch(void* const* d_in, const int* in_sizes, int n_in,
                              void* d_out, int out_size, void* d_ws,
                              size_t ws_size, hipStream_t stream) {
  const float* x = (const float*)d_in[0];
  const float* t = (const float*)d_in[1];
  const float* piou = (const float*)d_in[2];
  float* acc = (float*)d_ws;

  hipMemsetAsync(acc, 0, BATCH * 7 * sizeof(float), stream);
  loss_partial<<<BATCH * BLOCKS_PER_IMG, THREADS, 0, stream>>>(x, t, acc);
  loss_final<<<1, 64, 0, stream>>>(acc, piou, (float*)d_out);
}

// Round 3
// 149.195 us; speedup vs baseline: 1.0406x; 1.0159x over previous
//
#include <hip/hip_runtime.h>
#include <math.h>

// CellSegmentationLoss: fused focal + dice + boundary-BCE + IoU-aux loss.
// Inputs: d_in[0]=pred_masks (16*1*1024*1024 f32), d_in[1]=gt_masks (same),
//         d_in[2]=pred_iou (16 f32). Output: 1 f32 scalar.
//
// R3: force deep per-wave MLP. R2's compiler chose VGPR=32 and serialized the
// loads (load->wait->compute alternation, 4.4 B/cyc/CU achieved). Fix:
//   - all 16 dwordx4 loads issued up-front, pinned by sched_barrier(0)
//   - __launch_bounds__(256,4): VGPR cap 128 so the 64 data VGPRs survive
//   - 2048 blocks (8 blocks/CU, one residency round)

#define HW_PIX (1024 * 1024)
#define BATCH 16
constexpr int BLOCKS_PER_IMG = 128;
constexpr int THREADS = 256;
constexpr int PIX_PER_BLOCK = HW_PIX / BLOCKS_PER_IMG;        // 8192
constexpr int ITERS = PIX_PER_BLOCK / (THREADS * 4);          // 8 float4/thread/array

__global__ __launch_bounds__(THREADS, 4) void
loss_partial(const float* __restrict__ x, const float* __restrict__ t,
             float* __restrict__ acc) {
  const int b = blockIdx.x / BLOCKS_PER_IMG;
  const int chunk = blockIdx.x % BLOCKS_PER_IMG;
  const long base = (long)b * HW_PIX + (long)chunk * PIX_PER_BLOCK;
  const float4* __restrict__ x4 = (const float4*)(x + base);
  const float4* __restrict__ t4 = (const float4*)(t + base);

  // Issue ALL loads, then pin them above the compute with a full sched
  // barrier so the register allocator cannot re-sink them into the loop.
  float4 xv[ITERS], tv[ITERS];
#pragma unroll
  for (int i = 0; i < ITERS; ++i) {
    xv[i] = x4[threadIdx.x + i * THREADS];
    tv[i] = t4[threadIdx.x + i * THREADS];
  }
  __builtin_amdgcn_sched_barrier(0);

  float fsum = 0.f, csum = 0.f, isum = 0.f, psum = 0.f;
  unsigned tcnt = 0, bicnt = 0, bpcnt = 0;   // wave-uniform (ballot counts)

#pragma unroll
  for (int i = 0; i < ITERS; ++i) {
    const float* xs = reinterpret_cast<const float*>(&xv[i]);
    const float* ts = reinterpret_cast<const float*>(&tv[i]);
#pragma unroll
    for (int j = 0; j < 4; ++j) {
      const float xx = xs[j];
      const float tt = ts[j];
      const float e = __expf(-fabsf(xx));               // exp(-|x|) in (0,1]
      const float s = 1.0f + e;
      const float r = __builtin_amdgcn_rcpf(s);
      const float p = (xx >= 0.0f) ? r : e * r;          // sigmoid(x)
      const float ce = fmaxf(xx, 0.0f) - xx * tt + __logf(s);
      const float om = fmaf(tt, 1.0f - 2.0f * p, p);     // 1 - p_t
      const float at = 0.75f - 0.5f * tt;                // alpha_t
      fsum += at * ce * om * om;
      csum += ce;
      isum = fmaf(p, tt, isum);
      psum += p;
      const unsigned long long mt = __ballot(tt != 0.0f);
      const unsigned long long mb = __ballot(xx > 0.0f); // p>0.5 <=> x>0
      tcnt  += (unsigned)__popcll(mt);
      bpcnt += (unsigned)__popcll(mb);
      bicnt += (unsigned)__popcll(mt & mb);
    }
  }

  __shared__ float red[THREADS / 64][7];
  const int lane = threadIdx.x & 63;
  const int wave = threadIdx.x >> 6;
  float vals[4] = {fsum, csum, isum, psum};
#pragma unroll
  for (int k = 0; k < 4; ++k) {
    float v = vals[k];
#pragma unroll
    for (int off = 32; off > 0; off >>= 1) v += __shfl_down(v, off);
    if (lane == 0) red[wave][k] = v;
  }
  if (lane == 0) {                 // counts are already wave totals
    red[wave][4] = (float)tcnt;
    red[wave][5] = (float)bicnt;
    red[wave][6] = (float)bpcnt;
  }
  __syncthreads();
  if (threadIdx.x < 7) {
    const float s = red[0][threadIdx.x] + red[1][threadIdx.x] +
                    red[2][threadIdx.x] + red[3][threadIdx.x];
    atomicAdd(&acc[b * 7 + threadIdx.x], s);
  }
}

__global__ void loss_final(const float* __restrict__ acc,
                           const float* __restrict__ pred_iou,
                           float* __restrict__ out) {
  constexpr float SMOOTH = 1e-6f;
  const int lane = threadIdx.x;  // one wave (64), lanes 0..15 active
  float F = 0.f, C = 0.f, D = 0.f, Q = 0.f;
  if (lane < BATCH) {
    const float* a = acc + lane * 7;
    F = a[0];
    C = a[1];
    const float I = a[2], P = a[3], T = a[4], BI = a[5], BP = a[6];
    D = (2.0f * I + SMOOTH) / (P + T + SMOOTH);            // dice term
    const float iou = (BI + SMOOTH) / (BP + T - BI + SMOOTH);
    const float d = pred_iou[lane] - iou;
    Q = d * d;
  }
#pragma unroll
  for (int off = 32; off > 0; off >>= 1) {
    F += __shfl_down(F, off);
    C += __shfl_down(C, off);
    D += __shfl_down(D, off);
    Q += __shfl_down(Q, off);
  }
  if (lane == 0) {
    const float invN = 1.0f / (float)((long)BATCH * HW_PIX);
    const float focal = F * invN;
    const float dice = 1.0f - D * (1.0f / (float)BATCH);
    const float half_boundary = C * invN;  // 0.5 * (2.0 * mean(ce))
    const float iou_loss = Q * (1.0f / (float)BATCH);
    out[0] = focal + dice + half_boundary + 0.1f * iou_loss;
  }
}

extern "C" void kernel_launch(void* const* d_in, const int* in_sizes, int n_in,
                              void* d_out, int out_size, void* d_ws,
                              size_t ws_size, hipStream_t stream) {
  const float* x = (const float*)d_in[0];
  const float* t = (const float*)d_in[1];
  const float* piou = (const float*)d_in[2];
  float* acc = (float*)d_ws;

  hipMemsetAsync(acc, 0, BATCH * 7 * sizeof(float), stream);
  loss_partial<<<BATCH * BLOCKS_PER_IMG, THREADS, 0, stream>>>(x, t, acc);
  loss_final<<<1, 64, 0, stream>>>(acc, piou, (float*)d_out);
}